// Round 5
// baseline (782.125 us; speedup 1.0000x reference)
//
#include <hip/hip_runtime.h>

// GATv2 2-layer encoder. R5: gat_edge restructured to 16-lanes-per-edge
// (4 edges per wave-iteration, 16 channels per lane) to amortize per-edge
// overhead; 1 wave per node restored. Fused Wl|Wr split-bf16 MFMA GEMM kept.
// N=50000, E=800000, IN=256, H=4, C=64, LAT=32, ED=3.

#define NN  50000
#define EE  800000
#define HC  256     // H*C
#define NSLOPE 0.2f

typedef float f32x4 __attribute__((ext_vector_type(4)));
typedef short bf16x8 __attribute__((ext_vector_type(8)));

__device__ __forceinline__ unsigned short f2b(float f) {   // fp32 -> bf16 RNE
    unsigned u = __float_as_uint(f);
    u += 0x7FFFu + ((u >> 16) & 1u);
    return (unsigned short)(u >> 16);
}
__device__ __forceinline__ float b2f(unsigned short h) {
    return __uint_as_float((unsigned)h << 16);
}

// ---------------- CSR build ----------------
__global__ __launch_bounds__(256) void deg_kernel(
    const int* __restrict__ dst, int* __restrict__ deg)
{
    int i = blockIdx.x * 256 + threadIdx.x;      // one int4 (4 edges) per thread
    if (i >= EE / 4) return;
    int4 v = ((const int4*)dst)[i];
    atomicAdd(&deg[v.x], 1);
    atomicAdd(&deg[v.y], 1);
    atomicAdd(&deg[v.z], 1);
    atomicAdd(&deg[v.w], 1);
}

__global__ __launch_bounds__(1024) void scan_kernel(
    const int* __restrict__ deg, int* __restrict__ row_start, int* __restrict__ cursor)
{
    __shared__ int sums[1024];
    const int tid = threadIdx.x;
    const int CH = (NN + 1023) / 1024;           // 49
    int b = tid * CH, e = min(b + CH, NN);
    int s = 0;
    for (int i = b; i < e; i++) s += deg[i];
    sums[tid] = s;
    __syncthreads();
    for (int off = 1; off < 1024; off <<= 1) {
        int v = (tid >= off) ? sums[tid - off] : 0;
        __syncthreads();
        sums[tid] += v;
        __syncthreads();
    }
    int run = (tid == 0) ? 0 : sums[tid - 1];
    for (int i = b; i < e; i++) {
        row_start[i] = run;
        cursor[i]    = run;
        run += deg[i];
    }
    if (tid == 0) row_start[NN] = EE;
}

__global__ __launch_bounds__(256) void scatter_kernel(
    const int* __restrict__ ei, const float* __restrict__ ea,
    int* __restrict__ cursor, float4* __restrict__ csr)
{
    int i = blockIdx.x * 256 + threadIdx.x;      // 4 edges per thread
    if (i >= EE / 4) return;
    int4 s = ((const int4*)ei)[i];
    int4 d = ((const int4*)(ei + EE))[i];
    float4 e0 = ((const float4*)ea)[i * 3 + 0];
    float4 e1 = ((const float4*)ea)[i * 3 + 1];
    float4 e2 = ((const float4*)ea)[i * 3 + 2];
    int p0 = atomicAdd(&cursor[d.x], 1);
    int p1 = atomicAdd(&cursor[d.y], 1);
    int p2 = atomicAdd(&cursor[d.z], 1);
    int p3 = atomicAdd(&cursor[d.w], 1);
    csr[p0] = make_float4(__int_as_float(s.x), e0.x, e0.y, e0.z);
    csr[p1] = make_float4(__int_as_float(s.y), e0.w, e1.x, e1.y);
    csr[p2] = make_float4(__int_as_float(s.z), e1.z, e1.w, e2.x);
    csr[p3] = make_float4(__int_as_float(s.w), e2.y, e2.z, e2.w);
}

// ---------------- W -> W^T split (bf16 hi/lo planes), once per weight ----------------
__global__ __launch_bounds__(256) void cvt_wt(
    const float* __restrict__ W, unsigned short* __restrict__ WTh,
    unsigned short* __restrict__ WTl, int K)
{
    int i = blockIdx.x * 256 + threadIdx.x;
    if (i >= K * 256) return;
    int k = i >> 8, c = i & 255;
    float v = W[i];
    unsigned short h = f2b(v);
    unsigned short l = f2b(v - b2f(h));
    WTh[(size_t)c * K + k] = h;
    WTl[(size_t)c * K + k] = l;
}

// ---------------- fused split-bf16 MFMA GEMM: [xl|xr] = A @ [Wl|Wr] + bias ----------
__global__ __launch_bounds__(256) void gemm_fused(
    const float* __restrict__ A,
    const unsigned short* __restrict__ BTh, const unsigned short* __restrict__ BTl,
    const float* __restrict__ bias0, const float* __restrict__ bias1,
    float* __restrict__ C0, float* __restrict__ C1,
    int M, int K)
{
    __shared__ unsigned short Ah[64][36], Al[64][36];    // 72B row stride: 18-bank spread
    __shared__ unsigned short Bh[256][36], Bl[256][36];  // total LDS 46080 B
    const int tid = threadIdx.x;
    const int bm = blockIdx.y << 6;
    const int bn = blockIdx.x << 8;        // 0 or 256
    const int w  = tid >> 6, l = tid & 63;
    const int wr = w >> 1, wc = w & 1;
    const int lr = l & 15, lk = l >> 4;

    f32x4 acc[2][8];
#pragma unroll
    for (int a = 0; a < 2; a++)
#pragma unroll
        for (int b = 0; b < 8; b++) acc[a][b] = (f32x4){0.f, 0.f, 0.f, 0.f};

    const int ar = tid >> 2, ac = (tid & 3) << 3;   // A stage: row 0..63, k-chunk {0,8,16,24}

    for (int k0 = 0; k0 < K; k0 += 32) {
        // ---- stage A (fp32 -> bf16 hi/lo split in registers) ----
        float av[8];
        if (bm + ar < M) {
            *(float4*)&av[0] = *(const float4*)&A[(size_t)(bm + ar) * K + k0 + ac];
            *(float4*)&av[4] = *(const float4*)&A[(size_t)(bm + ar) * K + k0 + ac + 4];
        } else {
#pragma unroll
            for (int j = 0; j < 8; j++) av[j] = 0.f;
        }
        unsigned hp[4], lp[4];
#pragma unroll
        for (int j = 0; j < 4; j++) {
            unsigned short h0 = f2b(av[2 * j]),     h1 = f2b(av[2 * j + 1]);
            unsigned short l0 = f2b(av[2 * j]     - b2f(h0));
            unsigned short l1 = f2b(av[2 * j + 1] - b2f(h1));
            hp[j] = (unsigned)h0 | ((unsigned)h1 << 16);
            lp[j] = (unsigned)l0 | ((unsigned)l1 << 16);
        }
        *(uint4*)&Ah[ar][ac] = make_uint4(hp[0], hp[1], hp[2], hp[3]);
        *(uint4*)&Al[ar][ac] = make_uint4(lp[0], lp[1], lp[2], lp[3]);
        // ---- stage B (bf16 planes, pure copy): 256 rows x 64B, 4 reps ----
#pragma unroll
        for (int rep = 0; rep < 4; rep++) {
            int i  = (rep << 8) + tid;
            int rb = i >> 2, cb = (i & 3) << 3;
            *(uint4*)&Bh[rb][cb] = *(const uint4*)&BTh[(size_t)(bn + rb) * K + k0 + cb];
            *(uint4*)&Bl[rb][cb] = *(const uint4*)&BTl[(size_t)(bn + rb) * K + k0 + cb];
        }
        __syncthreads();

        bf16x8 afh[2], afl[2];
#pragma unroll
        for (int a = 0; a < 2; a++) {
            afh[a] = *(const bf16x8*)&Ah[wr * 32 + a * 16 + lr][lk << 3];
            afl[a] = *(const bf16x8*)&Al[wr * 32 + a * 16 + lr][lk << 3];
        }
#pragma unroll
        for (int b = 0; b < 8; b++) {
            bf16x8 bh  = *(const bf16x8*)&Bh[wc * 128 + b * 16 + lr][lk << 3];
            bf16x8 bl_ = *(const bf16x8*)&Bl[wc * 128 + b * 16 + lr][lk << 3];
#pragma unroll
            for (int a = 0; a < 2; a++) {
                acc[a][b] = __builtin_amdgcn_mfma_f32_16x16x32_bf16(afh[a], bh,  acc[a][b], 0, 0, 0);
                acc[a][b] = __builtin_amdgcn_mfma_f32_16x16x32_bf16(afh[a], bl_, acc[a][b], 0, 0, 0);
                acc[a][b] = __builtin_amdgcn_mfma_f32_16x16x32_bf16(afl[a], bh,  acc[a][b], 0, 0, 0);
            }
        }
        __syncthreads();
    }

    const float* bias = (bn == 0) ? bias0 : bias1;
    float* C = (bn == 0) ? C0 : C1;
#pragma unroll
    for (int a = 0; a < 2; a++) {
        int rbase = bm + wr * 32 + a * 16 + (lk << 2);
#pragma unroll
        for (int b = 0; b < 8; b++) {
            int c = wc * 128 + b * 16 + lr;        // 0..255 within half
            float bs = bias[c];
#pragma unroll
            for (int i = 0; i < 4; i++) {
                int rg = rbase + i;
                if (rg < M) C[(size_t)rg * HC + c] = acc[a][b][i] + bs;
            }
        }
    }
}

// ---------------- Fused per-node edge attention + aggregation ----------------
// One wave per node. lane = g*16 + j: group g (0..3) owns edge it*4+g of the
// node's list; lane owns channels [j*16, j*16+16) (4 consecutive float4s).
// Head of lane's channels = j>>2, so alpha-reduce = shfl_xor(1,2) in the
// 4-lane quartet; group combine = shfl_xor(16,32); head mean = shfl_xor(4,8).
__global__ __launch_bounds__(256) void gat_edge(
    const float* __restrict__ xl, const float* __restrict__ xr,
    const float4* __restrict__ csr, const int* __restrict__ row_start,
    const float* __restrict__ att, const float* __restrict__ We,
    const float* __restrict__ bias, float* __restrict__ out)
{
    const int lane = threadIdx.x & 63;
    const int node = (blockIdx.x * 256 + threadIdx.x) >> 6;
    if (node >= NN) return;
    const int g = lane >> 4;
    const int j = lane & 15;
    const f32x4* xlv = (const f32x4*)xl;               // row = 64 float4s
    const int cb4 = j << 2;                            // float4 index of channel base

    // per-lane constants for 16 channels
    f32x4 w0[4], w1[4], w2[4], at[4], xr4[4];
#pragma unroll
    for (int q = 0; q < 4; q++) {
        w0[q]  = *(const f32x4*)&We[        (cb4 + q) * 4];
        w1[q]  = *(const f32x4*)&We[HC     + (cb4 + q) * 4];
        w2[q]  = *(const f32x4*)&We[2 * HC + (cb4 + q) * 4];
        at[q]  = *(const f32x4*)&att[       (cb4 + q) * 4];
        xr4[q] = xlv[0];                               // placeholder, set below
    }
    {
        const f32x4* xrv = (const f32x4*)xr;
#pragma unroll
        for (int q = 0; q < 4; q++) xr4[q] = xrv[(size_t)node * 64 + cb4 + q];
    }

    f32x4 acc[4];
#pragma unroll
    for (int q = 0; q < 4; q++) acc[q] = (f32x4){0.f, 0.f, 0.f, 0.f};
    float denom = 0.f, eas0 = 0.f, eas1 = 0.f, eas2 = 0.f;

    const int beg = row_start[node];
    const int n   = row_start[node + 1] - beg;
    const float4* cp = csr + beg;
    const int nit = (n + 3) >> 2;

    // pipeline: load edge idx = g, gather its xl slice
    int idx = g;
    bool val = idx < n;
    float4 rec = val ? cp[idx] : make_float4(0.f, 0.f, 0.f, 0.f);
    f32x4 xv0, xv1, xv2, xv3;
    {
        int s = val ? __float_as_int(rec.x) : node;
        const f32x4* gp = xlv + (size_t)s * 64 + cb4;
        xv0 = gp[0]; xv1 = gp[1]; xv2 = gp[2]; xv3 = gp[3];
    }

    for (int it = 0; it < nit; it++) {
        const bool  cv = val;
        const float4 crec = rec;
        f32x4 c0 = xv0, c1 = xv1, c2 = xv2, c3 = xv3;
        idx += 4;
        val = idx < n;
        if (val) {
            rec = cp[idx];
            const f32x4* gp = xlv + (size_t)__float_as_int(rec.x) * 64 + cb4;
            xv0 = gp[0]; xv1 = gp[1]; xv2 = gp[2]; xv3 = gp[3];
        } else {
            rec = make_float4(0.f, 0.f, 0.f, 0.f);
        }

        const float ea0 = crec.y, ea1 = crec.z, ea2 = crec.w;
        eas0 += ea0; eas1 += ea1; eas2 += ea2;         // zeros when invalid

        float p = 0.f;
        f32x4 cx[4] = {c0, c1, c2, c3};
#pragma unroll
        for (int q = 0; q < 4; q++) {
            f32x4 m = cx[q] + xr4[q];
            m += ea0 * w0[q];
            m += ea1 * w1[q];
            m += ea2 * w2[q];
#pragma unroll
            for (int t = 0; t < 4; t++) m[t] = fmaxf(m[t], NSLOPE * m[t]);
#pragma unroll
            for (int t = 0; t < 4; t++) p = fmaf(m[t], at[q][t], p);
            cx[q] = m;   // dead; keeps compiler from re-deriving (m unused after)
        }
        p += __shfl_xor(p, 1);
        p += __shfl_xor(p, 2);                         // alpha for head j>>2
        float ex = cv ? __expf(p) : 0.f;               // softmax shift-free (alpha O(1))
        denom += ex;
        acc[0] += ex * c0;
        acc[1] += ex * c1;
        acc[2] += ex * c2;
        acc[3] += ex * c3;
    }

    // combine the 4 edge-groups
    float* af = (float*)acc;
#pragma unroll
    for (int k = 0; k < 16; k++) {
        af[k] += __shfl_xor(af[k], 16);
        af[k] += __shfl_xor(af[k], 32);
    }
    denom += __shfl_xor(denom, 16); denom += __shfl_xor(denom, 32);
    eas0  += __shfl_xor(eas0, 16);  eas0  += __shfl_xor(eas0, 32);
    eas1  += __shfl_xor(eas1, 16);  eas1  += __shfl_xor(eas1, 32);
    eas2  += __shfl_xor(eas2, 16);  eas2  += __shfl_xor(eas2, 32);

    {   // self loop: attr = mean of incoming edge attrs (0 if none)
        const float rd = 1.0f / fmaxf((float)n, 1.0f);
        const float ea0 = eas0 * rd, ea1 = eas1 * rd, ea2 = eas2 * rd;
        const f32x4* gp = xlv + (size_t)node * 64 + cb4;
        f32x4 sv[4] = {gp[0], gp[1], gp[2], gp[3]};
        float p = 0.f;
#pragma unroll
        for (int q = 0; q < 4; q++) {
            f32x4 m = sv[q] + xr4[q];
            m += ea0 * w0[q];
            m += ea1 * w1[q];
            m += ea2 * w2[q];
#pragma unroll
            for (int t = 0; t < 4; t++) m[t] = fmaxf(m[t], NSLOPE * m[t]);
#pragma unroll
            for (int t = 0; t < 4; t++) p = fmaf(m[t], at[q][t], p);
        }
        p += __shfl_xor(p, 1);
        p += __shfl_xor(p, 2);
        float ex = __expf(p);                          // identical across groups
        denom += ex;
        acc[0] += ex * sv[0];
        acc[1] += ex * sv[1];
        acc[2] += ex * sv[2];
        acc[3] += ex * sv[3];
    }

    // normalize (per-head denom), then mean over heads: lanes j, j^4, j^8, j^12
    const float inv = 1.0f / denom;
#pragma unroll
    for (int k = 0; k < 16; k++) {
        float r = af[k] * inv;
        r += __shfl_xor(r, 4);
        r += __shfl_xor(r, 8);
        af[k] = r;
    }
    if (lane < 4) {                                    // g==0, j<4: 4 lanes x 16 ch = 64
        const f32x4* bv = (const f32x4*)bias;
        f32x4* ov = (f32x4*)out;
#pragma unroll
        for (int q = 0; q < 4; q++) {
            f32x4 o = 0.25f * acc[q] + bv[cb4 + q];
#pragma unroll
            for (int t = 0; t < 4; t++) o[t] = fmaxf(o[t], 0.f);
            ov[(size_t)node * 16 + cb4 + q] = o;
        }
    }
}

// ---------------- final linear: out[N x 32] = h[N x 64] @ Wmu + bmu ----------------
__global__ __launch_bounds__(256) void mu_kernel(
    const float* __restrict__ h, const float* __restrict__ Wmu,
    const float* __restrict__ bmu, float* __restrict__ out)
{
    __shared__ float ws[64 * 32];
    __shared__ float hs[8 * 64];
    const int tid = threadIdx.x;
#pragma unroll
    for (int i = 0; i < 8; i++) ws[tid + i * 256] = Wmu[tid + i * 256];
    const int nb = blockIdx.x * 8;   // 8 nodes/block, NN % 8 == 0
    {
        int idx = tid * 2;
        *(float2*)&hs[idx] = *(const float2*)&h[(size_t)nb * 64 + idx];
    }
    __syncthreads();
    const int ln = tid >> 5;     // 0..7
    const int o  = tid & 31;
    float acc = bmu[o];
#pragma unroll
    for (int k = 0; k < 64; k++) acc = fmaf(hs[ln * 64 + k], ws[k * 32 + o], acc);
    out[(size_t)(nb + ln) * 32 + o] = acc;
}

// ---------------- launch ----------------
extern "C" void kernel_launch(void* const* d_in, const int* in_sizes, int n_in,
                              void* d_out, int out_size, void* d_ws, size_t ws_size,
                              hipStream_t stream) {
    const float* x    = (const float*)d_in[0];
    const int*   ei   = (const int*)  d_in[1];
    const float* ea   = (const float*)d_in[2];
    const float* Wl0  = (const float*)d_in[3];
    const float* bl0  = (const float*)d_in[4];
    const float* Wr0  = (const float*)d_in[5];
    const float* br0  = (const float*)d_in[6];
    const float* We0  = (const float*)d_in[7];
    const float* att0 = (const float*)d_in[8];
    const float* bi0  = (const float*)d_in[9];
    const float* Wl1  = (const float*)d_in[10];
    const float* bl1  = (const float*)d_in[11];
    const float* Wr1  = (const float*)d_in[12];
    const float* br1  = (const float*)d_in[13];
    const float* We1  = (const float*)d_in[14];
    const float* att1 = (const float*)d_in[15];
    const float* bi1  = (const float*)d_in[16];
    const float* Wmu  = (const float*)d_in[17];
    const float* bmu  = (const float*)d_in[18];
    float* out = (float*)d_out;

    // workspace carve-up (~129.2 MB, same footprint class as proven R1-R4)
    float* xl32 = (float*)d_ws;                        // NN*256
    float* xr32 = xl32 + (size_t)NN * HC;              // NN*256
    float* h1   = xr32 + (size_t)NN * HC;              // NN*64
    int*   deg  = (int*)(h1 + (size_t)NN * 64);        // NN
    int*   rows = deg + NN;                            // NN+1
    int*   curs = rows + NN + 1;                       // NN
    uintptr_t p = (uintptr_t)(curs + NN);
    p = (p + 15) & ~(uintptr_t)15;
    unsigned short* WT0h = (unsigned short*)p;         // [512][256]
    unsigned short* WT0l = WT0h + 512 * 256;
    unsigned short* WT1h = WT0l + 512 * 256;           // [512][64]
    unsigned short* WT1l = WT1h + 512 * 64;
    p = (uintptr_t)(WT1l + 512 * 64);
    p = (p + 255) & ~(uintptr_t)255;
    float4* csr = (float4*)p;                          // EE records

    // CSR build (shared by both layers)
    hipMemsetAsync(deg, 0, NN * sizeof(int), stream);
    deg_kernel<<<(EE / 4 + 255) / 256, 256, 0, stream>>>(ei + EE, deg);
    scan_kernel<<<1, 1024, 0, stream>>>(deg, rows, curs);
    scatter_kernel<<<(EE / 4 + 255) / 256, 256, 0, stream>>>(ei, ea, curs, csr);

    // weight transpose+split into fused [512][K] planes (tiny, once)
    cvt_wt<<<256, 256, 0, stream>>>(Wl0, WT0h,             WT0l,             256);
    cvt_wt<<<256, 256, 0, stream>>>(Wr0, WT0h + 256 * 256, WT0l + 256 * 256, 256);
    cvt_wt<<< 64, 256, 0, stream>>>(Wl1, WT1h,             WT1l,             64);
    cvt_wt<<< 64, 256, 0, stream>>>(Wr1, WT1h + 256 * 64,  WT1l + 256 * 64,  64);

    dim3 gg(2, (NN + 63) / 64);
    const int gat_grid = (NN * 64) / 256;   // one wave per node

    // layer 0
    gemm_fused<<<gg, 256, 0, stream>>>(x, WT0h, WT0l, bl0, br0, xl32, xr32, NN, 256);
    gat_edge<<<gat_grid, 256, 0, stream>>>(xl32, xr32, csr, rows, att0, We0, bi0, h1);

    // layer 1
    gemm_fused<<<gg, 256, 0, stream>>>(h1, WT1h, WT1l, bl1, br1, xl32, xr32, NN, 64);
    gat_edge<<<gat_grid, 256, 0, stream>>>(xl32, xr32, csr, rows, att1, We1, bi1, h1);

    // head
    mu_kernel<<<NN / 8, 256, 0, stream>>>(h1, Wmu, bmu, out);
}

// Round 6
// 598.744 us; speedup vs baseline: 1.3063x; 1.3063x over previous
//
#include <hip/hip_runtime.h>

// GATv2 2-layer encoder. R6: gat_edge reverted to the R3 structure (best
// measured: 135us, VALUBusy 81%) + 32-bit gather addressing; single-block
// scan replaced by 3-kernel device-wide scan. Fused Wl|Wr MFMA GEMM kept.
// N=50000, E=800000, IN=256, H=4, C=64, LAT=32, ED=3.

#define NN  50000
#define EE  800000
#define HC  256     // H*C
#define NSLOPE 0.2f
#define SCAN_B ((NN + 255) / 256)   // 196 scan blocks

typedef float f32x4 __attribute__((ext_vector_type(4)));
typedef short bf16x8 __attribute__((ext_vector_type(8)));

__device__ __forceinline__ unsigned short f2b(float f) {   // fp32 -> bf16 RNE
    unsigned u = __float_as_uint(f);
    u += 0x7FFFu + ((u >> 16) & 1u);
    return (unsigned short)(u >> 16);
}
__device__ __forceinline__ float b2f(unsigned short h) {
    return __uint_as_float((unsigned)h << 16);
}

// ---------------- CSR build ----------------
__global__ __launch_bounds__(256) void deg_kernel(
    const int* __restrict__ dst, int* __restrict__ deg)
{
    int i = blockIdx.x * 256 + threadIdx.x;      // one int4 (4 edges) per thread
    if (i >= EE / 4) return;
    int4 v = ((const int4*)dst)[i];
    atomicAdd(&deg[v.x], 1);
    atomicAdd(&deg[v.y], 1);
    atomicAdd(&deg[v.z], 1);
    atomicAdd(&deg[v.w], 1);
}

// device-wide exclusive scan of deg -> rows, in 3 small kernels
__global__ __launch_bounds__(256) void scan1_kernel(
    const int* __restrict__ deg, int* __restrict__ rows, int* __restrict__ bsum)
{
    __shared__ int sh[256];
    const int t = threadIdx.x, b = blockIdx.x;
    const int i = b * 256 + t;
    int v = (i < NN) ? deg[i] : 0;
    sh[t] = v;
    __syncthreads();
    for (int off = 1; off < 256; off <<= 1) {
        int u = (t >= off) ? sh[t - off] : 0;
        __syncthreads();
        sh[t] += u;
        __syncthreads();
    }
    if (i < NN) rows[i] = sh[t] - v;             // exclusive within block
    if (t == 255) bsum[b] = sh[255];
}

__global__ __launch_bounds__(256) void scan2_kernel(int* __restrict__ bsum, int* __restrict__ boff)
{
    __shared__ int sh[256];
    const int t = threadIdx.x;
    int v = (t < SCAN_B) ? bsum[t] : 0;
    sh[t] = v;
    __syncthreads();
    for (int off = 1; off < 256; off <<= 1) {
        int u = (t >= off) ? sh[t - off] : 0;
        __syncthreads();
        sh[t] += u;
        __syncthreads();
    }
    if (t < SCAN_B) boff[t] = sh[t] - v;         // exclusive block offsets
}

__global__ __launch_bounds__(256) void scan3_kernel(
    int* __restrict__ rows, int* __restrict__ curs, const int* __restrict__ boff)
{
    const int b = blockIdx.x;
    const int i = b * 256 + threadIdx.x;
    if (i < NN) {
        int v = rows[i] + boff[b];
        rows[i] = v;
        curs[i] = v;
    }
    if (i == 0) rows[NN] = EE;
}

__global__ __launch_bounds__(256) void scatter_kernel(
    const int* __restrict__ ei, const float* __restrict__ ea,
    int* __restrict__ cursor, float4* __restrict__ csr)
{
    int i = blockIdx.x * 256 + threadIdx.x;      // 4 edges per thread
    if (i >= EE / 4) return;
    int4 s = ((const int4*)ei)[i];
    int4 d = ((const int4*)(ei + EE))[i];
    float4 e0 = ((const float4*)ea)[i * 3 + 0];
    float4 e1 = ((const float4*)ea)[i * 3 + 1];
    float4 e2 = ((const float4*)ea)[i * 3 + 2];
    int p0 = atomicAdd(&cursor[d.x], 1);
    int p1 = atomicAdd(&cursor[d.y], 1);
    int p2 = atomicAdd(&cursor[d.z], 1);
    int p3 = atomicAdd(&cursor[d.w], 1);
    csr[p0] = make_float4(__int_as_float(s.x), e0.x, e0.y, e0.z);
    csr[p1] = make_float4(__int_as_float(s.y), e0.w, e1.x, e1.y);
    csr[p2] = make_float4(__int_as_float(s.z), e1.z, e1.w, e2.x);
    csr[p3] = make_float4(__int_as_float(s.w), e2.y, e2.z, e2.w);
}

// ---------------- W -> W^T split (bf16 hi/lo planes), once per weight ----------------
__global__ __launch_bounds__(256) void cvt_wt(
    const float* __restrict__ W, unsigned short* __restrict__ WTh,
    unsigned short* __restrict__ WTl, int K)
{
    int i = blockIdx.x * 256 + threadIdx.x;
    if (i >= K * 256) return;
    int k = i >> 8, c = i & 255;
    float v = W[i];
    unsigned short h = f2b(v);
    unsigned short l = f2b(v - b2f(h));
    WTh[(size_t)c * K + k] = h;
    WTl[(size_t)c * K + k] = l;
}

// ---------------- fused split-bf16 MFMA GEMM: [xl|xr] = A @ [Wl|Wr] + bias ----------
__global__ __launch_bounds__(256) void gemm_fused(
    const float* __restrict__ A,
    const unsigned short* __restrict__ BTh, const unsigned short* __restrict__ BTl,
    const float* __restrict__ bias0, const float* __restrict__ bias1,
    float* __restrict__ C0, float* __restrict__ C1,
    int M, int K)
{
    __shared__ unsigned short Ah[64][36], Al[64][36];    // 72B row stride: conflict-free
    __shared__ unsigned short Bh[256][36], Bl[256][36];  // total LDS 46080 B
    const int tid = threadIdx.x;
    const int bm = blockIdx.y << 6;
    const int bn = blockIdx.x << 8;        // 0 or 256
    const int w  = tid >> 6, l = tid & 63;
    const int wr = w >> 1, wc = w & 1;
    const int lr = l & 15, lk = l >> 4;

    f32x4 acc[2][8];
#pragma unroll
    for (int a = 0; a < 2; a++)
#pragma unroll
        for (int b = 0; b < 8; b++) acc[a][b] = (f32x4){0.f, 0.f, 0.f, 0.f};

    const int ar = tid >> 2, ac = (tid & 3) << 3;   // A stage: row 0..63, k-chunk {0,8,16,24}

    for (int k0 = 0; k0 < K; k0 += 32) {
        // ---- stage A (fp32 -> bf16 hi/lo split in registers) ----
        float av[8];
        if (bm + ar < M) {
            *(float4*)&av[0] = *(const float4*)&A[(size_t)(bm + ar) * K + k0 + ac];
            *(float4*)&av[4] = *(const float4*)&A[(size_t)(bm + ar) * K + k0 + ac + 4];
        } else {
#pragma unroll
            for (int j = 0; j < 8; j++) av[j] = 0.f;
        }
        unsigned hp[4], lp[4];
#pragma unroll
        for (int j = 0; j < 4; j++) {
            unsigned short h0 = f2b(av[2 * j]),     h1 = f2b(av[2 * j + 1]);
            unsigned short l0 = f2b(av[2 * j]     - b2f(h0));
            unsigned short l1 = f2b(av[2 * j + 1] - b2f(h1));
            hp[j] = (unsigned)h0 | ((unsigned)h1 << 16);
            lp[j] = (unsigned)l0 | ((unsigned)l1 << 16);
        }
        *(uint4*)&Ah[ar][ac] = make_uint4(hp[0], hp[1], hp[2], hp[3]);
        *(uint4*)&Al[ar][ac] = make_uint4(lp[0], lp[1], lp[2], lp[3]);
        // ---- stage B (bf16 planes, pure copy): 256 rows x 64B, 4 reps ----
#pragma unroll
        for (int rep = 0; rep < 4; rep++) {
            int i  = (rep << 8) + tid;
            int rb = i >> 2, cb = (i & 3) << 3;
            *(uint4*)&Bh[rb][cb] = *(const uint4*)&BTh[(size_t)(bn + rb) * K + k0 + cb];
            *(uint4*)&Bl[rb][cb] = *(const uint4*)&BTl[(size_t)(bn + rb) * K + k0 + cb];
        }
        __syncthreads();

        bf16x8 afh[2], afl[2];
#pragma unroll
        for (int a = 0; a < 2; a++) {
            afh[a] = *(const bf16x8*)&Ah[wr * 32 + a * 16 + lr][lk << 3];
            afl[a] = *(const bf16x8*)&Al[wr * 32 + a * 16 + lr][lk << 3];
        }
#pragma unroll
        for (int b = 0; b < 8; b++) {
            bf16x8 bh  = *(const bf16x8*)&Bh[wc * 128 + b * 16 + lr][lk << 3];
            bf16x8 bl_ = *(const bf16x8*)&Bl[wc * 128 + b * 16 + lr][lk << 3];
#pragma unroll
            for (int a = 0; a < 2; a++) {
                acc[a][b] = __builtin_amdgcn_mfma_f32_16x16x32_bf16(afh[a], bh,  acc[a][b], 0, 0, 0);
                acc[a][b] = __builtin_amdgcn_mfma_f32_16x16x32_bf16(afh[a], bl_, acc[a][b], 0, 0, 0);
                acc[a][b] = __builtin_amdgcn_mfma_f32_16x16x32_bf16(afl[a], bh,  acc[a][b], 0, 0, 0);
            }
        }
        __syncthreads();
    }

    const float* bias = (bn == 0) ? bias0 : bias1;
    float* C = (bn == 0) ? C0 : C1;
#pragma unroll
    for (int a = 0; a < 2; a++) {
        int rbase = bm + wr * 32 + a * 16 + (lk << 2);
#pragma unroll
        for (int b = 0; b < 8; b++) {
            int c = wc * 128 + b * 16 + lr;        // 0..255 within half
            float bs = bias[c];
#pragma unroll
            for (int i = 0; i < 4; i++) {
                int rg = rbase + i;
                if (rg < M) C[(size_t)rg * HC + c] = acc[a][b][i] + bs;
            }
        }
    }
}

// ---------------- Fused per-node edge attention + aggregation (R3 structure) --------
// One wave per node. lane = h*16 + q; lane owns channels [4q..4q+3] of head h.
// rec pipeline 3-deep, xl-gather pipeline 2-deep. 32-bit gather indices.
__global__ __launch_bounds__(256) void gat_edge(
    const float* __restrict__ xl, const float* __restrict__ xr,
    const float4* __restrict__ csr, const int* __restrict__ row_start,
    const float* __restrict__ att, const float* __restrict__ We,
    const float* __restrict__ bias, float* __restrict__ out)
{
    const int lane = threadIdx.x & 63;
    const int node = (blockIdx.x * 256 + threadIdx.x) >> 6;
    if (node >= NN) return;
    const int j4 = lane << 2;
    const float4* xlv = (const float4*)xl;     // node row = 64 float4s

    const float4 xr4 = *(const float4*)&xr[(size_t)node * HC + j4];
    const float4 at4 = *(const float4*)&att[j4];
    const float4 w0  = *(const float4*)&We[j4];
    const float4 w1  = *(const float4*)&We[HC + j4];
    const float4 w2  = *(const float4*)&We[2 * HC + j4];

    float acc0 = 0.f, acc1 = 0.f, acc2 = 0.f, acc3 = 0.f, denom = 0.f;
    float eas0 = 0.f, eas1 = 0.f, eas2 = 0.f;
    const int beg = row_start[node];
    const int n   = row_start[node + 1] - beg;
    const float4* cp = csr + beg;

    float4 r0 = {0,0,0,0}, r1 = {0,0,0,0}, r2 = {0,0,0,0};
    float4 v0 = {0,0,0,0}, v1 = {0,0,0,0};
    if (n > 0) { r0 = cp[0]; v0 = xlv[(unsigned)(__float_as_int(r0.x) * 64 + lane)]; }
    if (n > 1) { r1 = cp[1]; v1 = xlv[(unsigned)(__float_as_int(r1.x) * 64 + lane)]; }
    if (n > 2) { r2 = cp[2]; }

    for (int i = 0; i < n; i++) {
        float4 crec = r0, cxv = v0;
        r0 = r1; r1 = r2; v0 = v1;
        if (i + 3 < n) r2 = cp[i + 3];
        if (i + 2 < n) v1 = xlv[(unsigned)(__float_as_int(r1.x) * 64 + lane)];

        float ea0 = crec.y, ea1 = crec.z, ea2 = crec.w;
        eas0 += ea0; eas1 += ea1; eas2 += ea2;
        float m0 = cxv.x + xr4.x + ea0 * w0.x + ea1 * w1.x + ea2 * w2.x;
        float m1 = cxv.y + xr4.y + ea0 * w0.y + ea1 * w1.y + ea2 * w2.y;
        float m2 = cxv.z + xr4.z + ea0 * w0.z + ea1 * w1.z + ea2 * w2.z;
        float m3 = cxv.w + xr4.w + ea0 * w0.w + ea1 * w1.w + ea2 * w2.w;
        m0 = fmaxf(m0, NSLOPE * m0);           // leaky-relu as single v_max
        m1 = fmaxf(m1, NSLOPE * m1);
        m2 = fmaxf(m2, NSLOPE * m2);
        m3 = fmaxf(m3, NSLOPE * m3);
        float p = m0 * at4.x + m1 * at4.y + m2 * at4.z + m3 * at4.w;
        p += __shfl_xor(p, 1);
        p += __shfl_xor(p, 2);
        p += __shfl_xor(p, 4);
        p += __shfl_xor(p, 8);
        // softmax shift-invariant; alpha O(1) so no max subtraction needed
        float ex = __expf(p);
        denom += ex;
        acc0 = fmaf(ex, cxv.x, acc0);
        acc1 = fmaf(ex, cxv.y, acc1);
        acc2 = fmaf(ex, cxv.z, acc2);
        acc3 = fmaf(ex, cxv.w, acc3);
    }

    {   // self loop: attr = mean of incoming edge attrs (0 if none)
        float rd = 1.0f / fmaxf((float)n, 1.0f);
        float ea0 = eas0 * rd, ea1 = eas1 * rd, ea2 = eas2 * rd;
        float4 sv = xlv[(unsigned)(node * 64 + lane)];
        float m0 = sv.x + xr4.x + ea0 * w0.x + ea1 * w1.x + ea2 * w2.x;
        float m1 = sv.y + xr4.y + ea0 * w0.y + ea1 * w1.y + ea2 * w2.y;
        float m2 = sv.z + xr4.z + ea0 * w0.z + ea1 * w1.z + ea2 * w2.z;
        float m3 = sv.w + xr4.w + ea0 * w0.w + ea1 * w1.w + ea2 * w2.w;
        m0 = fmaxf(m0, NSLOPE * m0);
        m1 = fmaxf(m1, NSLOPE * m1);
        m2 = fmaxf(m2, NSLOPE * m2);
        m3 = fmaxf(m3, NSLOPE * m3);
        float p = m0 * at4.x + m1 * at4.y + m2 * at4.z + m3 * at4.w;
        p += __shfl_xor(p, 1);
        p += __shfl_xor(p, 2);
        p += __shfl_xor(p, 4);
        p += __shfl_xor(p, 8);
        float ex = __expf(p);
        denom += ex;
        acc0 = fmaf(ex, sv.x, acc0);
        acc1 = fmaf(ex, sv.y, acc1);
        acc2 = fmaf(ex, sv.z, acc2);
        acc3 = fmaf(ex, sv.w, acc3);
    }

    const float inv = 1.0f / denom;
    float r0s = acc0 * inv, r1s = acc1 * inv, r2s = acc2 * inv, r3s = acc3 * inv;
    // head mean: lanes l, l+16, l+32, l+48 hold heads 0..3 of the same channels
    r0s += __shfl_xor(r0s, 16); r0s += __shfl_xor(r0s, 32);
    r1s += __shfl_xor(r1s, 16); r1s += __shfl_xor(r1s, 32);
    r2s += __shfl_xor(r2s, 16); r2s += __shfl_xor(r2s, 32);
    r3s += __shfl_xor(r3s, 16); r3s += __shfl_xor(r3s, 32);
    if (lane < 16) {
        float4 bv = *(const float4*)&bias[j4];
        float4 o;
        o.x = fmaxf(0.25f * r0s + bv.x, 0.f);   // mean over H=4 heads, +bias, ReLU
        o.y = fmaxf(0.25f * r1s + bv.y, 0.f);
        o.z = fmaxf(0.25f * r2s + bv.z, 0.f);
        o.w = fmaxf(0.25f * r3s + bv.w, 0.f);
        *(float4*)&out[(size_t)node * 64 + j4] = o;
    }
}

// ---------------- final linear: out[N x 32] = h[N x 64] @ Wmu + bmu ----------------
__global__ __launch_bounds__(256) void mu_kernel(
    const float* __restrict__ h, const float* __restrict__ Wmu,
    const float* __restrict__ bmu, float* __restrict__ out)
{
    __shared__ float ws[64 * 32];
    __shared__ float hs[8 * 64];
    const int tid = threadIdx.x;
#pragma unroll
    for (int i = 0; i < 8; i++) ws[tid + i * 256] = Wmu[tid + i * 256];
    const int nb = blockIdx.x * 8;   // 8 nodes/block, NN % 8 == 0
    {
        int idx = tid * 2;
        *(float2*)&hs[idx] = *(const float2*)&h[(size_t)nb * 64 + idx];
    }
    __syncthreads();
    const int ln = tid >> 5;     // 0..7
    const int o  = tid & 31;
    float acc = bmu[o];
#pragma unroll
    for (int k = 0; k < 64; k++) acc = fmaf(hs[ln * 64 + k], ws[k * 32 + o], acc);
    out[(size_t)(nb + ln) * 32 + o] = acc;
}

// ---------------- launch ----------------
extern "C" void kernel_launch(void* const* d_in, const int* in_sizes, int n_in,
                              void* d_out, int out_size, void* d_ws, size_t ws_size,
                              hipStream_t stream) {
    const float* x    = (const float*)d_in[0];
    const int*   ei   = (const int*)  d_in[1];
    const float* ea   = (const float*)d_in[2];
    const float* Wl0  = (const float*)d_in[3];
    const float* bl0  = (const float*)d_in[4];
    const float* Wr0  = (const float*)d_in[5];
    const float* br0  = (const float*)d_in[6];
    const float* We0  = (const float*)d_in[7];
    const float* att0 = (const float*)d_in[8];
    const float* bi0  = (const float*)d_in[9];
    const float* Wl1  = (const float*)d_in[10];
    const float* bl1  = (const float*)d_in[11];
    const float* Wr1  = (const float*)d_in[12];
    const float* br1  = (const float*)d_in[13];
    const float* We1  = (const float*)d_in[14];
    const float* att1 = (const float*)d_in[15];
    const float* bi1  = (const float*)d_in[16];
    const float* Wmu  = (const float*)d_in[17];
    const float* bmu  = (const float*)d_in[18];
    float* out = (float*)d_out;

    // workspace carve-up (~129.2 MB)
    float* xl32 = (float*)d_ws;                        // NN*256
    float* xr32 = xl32 + (size_t)NN * HC;              // NN*256
    float* h1   = xr32 + (size_t)NN * HC;              // NN*64
    int*   deg  = (int*)(h1 + (size_t)NN * 64);        // NN
    int*   rows = deg + NN;                            // NN+1
    int*   curs = rows + NN + 1;                       // NN
    int*   bsum = curs + NN;                           // SCAN_B
    int*   boff = bsum + SCAN_B;                       // SCAN_B
    uintptr_t p = (uintptr_t)(boff + SCAN_B);
    p = (p + 15) & ~(uintptr_t)15;
    unsigned short* WT0h = (unsigned short*)p;         // [512][256]
    unsigned short* WT0l = WT0h + 512 * 256;
    unsigned short* WT1h = WT0l + 512 * 256;           // [512][64]
    unsigned short* WT1l = WT1h + 512 * 64;
    p = (uintptr_t)(WT1l + 512 * 64);
    p = (p + 255) & ~(uintptr_t)255;
    float4* csr = (float4*)p;                          // EE records

    // CSR build (shared by both layers)
    hipMemsetAsync(deg, 0, NN * sizeof(int), stream);
    deg_kernel<<<(EE / 4 + 255) / 256, 256, 0, stream>>>(ei + EE, deg);
    scan1_kernel<<<SCAN_B, 256, 0, stream>>>(deg, rows, bsum);
    scan2_kernel<<<1, 256, 0, stream>>>(bsum, boff);
    scan3_kernel<<<SCAN_B, 256, 0, stream>>>(rows, curs, boff);
    scatter_kernel<<<(EE / 4 + 255) / 256, 256, 0, stream>>>(ei, ea, curs, csr);

    // weight transpose+split into fused [512][K] planes (tiny, once)
    cvt_wt<<<256, 256, 0, stream>>>(Wl0, WT0h,             WT0l,             256);
    cvt_wt<<<256, 256, 0, stream>>>(Wr0, WT0h + 256 * 256, WT0l + 256 * 256, 256);
    cvt_wt<<< 64, 256, 0, stream>>>(Wl1, WT1h,             WT1l,             64);
    cvt_wt<<< 64, 256, 0, stream>>>(Wr1, WT1h + 256 * 64,  WT1l + 256 * 64,  64);

    dim3 gg(2, (NN + 63) / 64);
    const int gat_grid = (NN * 64) / 256;   // one wave per node

    // layer 0
    gemm_fused<<<gg, 256, 0, stream>>>(x, WT0h, WT0l, bl0, br0, xl32, xr32, NN, 256);
    gat_edge<<<gat_grid, 256, 0, stream>>>(xl32, xr32, csr, rows, att0, We0, bi0, h1);

    // layer 1
    gemm_fused<<<gg, 256, 0, stream>>>(h1, WT1h, WT1l, bl1, br1, xl32, xr32, NN, 64);
    gat_edge<<<gat_grid, 256, 0, stream>>>(xl32, xr32, csr, rows, att1, We1, bi1, h1);

    // head
    mu_kernel<<<NN / 8, 256, 0, stream>>>(h1, Wmu, bmu, out);
}